// Round 14
// baseline (132.691 us; speedup 1.0000x reference)
//
#include <hip/hip_runtime.h>
#include <hip/hip_bf16.h>

#define FEATS 768
#define HEADS 12
#define HD    64
#define BB    128
#define NN    197
#define M_TOT (BB * NN)   // 25216 = 64 * 394 exactly
#define SCALE_INV (3.6084391824351615e-02f)  // 1/sqrt(768)
#define VS    216          // Vtl row stride in shorts

typedef __bf16 bf16x8 __attribute__((ext_vector_type(8)));
typedef float  f32x4  __attribute__((ext_vector_type(4)));
typedef unsigned short u16x8 __attribute__((ext_vector_type(8)));

__device__ __forceinline__ unsigned short f2bf1(float f) {
    __bf16 h = (__bf16)f;
    return *(unsigned short*)&h;
}
__device__ __forceinline__ unsigned int f2bf2(float lo, float hi) {
    return (unsigned int)f2bf1(lo) | ((unsigned int)f2bf1(hi) << 16);
}

// ---------------------------------------------------------------------------
// K0: merged prep. Blocks 0..11: W_qkv -> Wt_sw (validated R4+ swizzle).
// Blocks 12..587: W_out f32 [k][n] -> bf16 Wt [n][k] (plain, validated).
// ---------------------------------------------------------------------------
__global__ __launch_bounds__(256) void prep_kernel(
    const float* __restrict__ Wqkv, unsigned short* __restrict__ Wt_sw,
    const float* __restrict__ W,    unsigned short* __restrict__ Wt)
{
    __shared__ __align__(16) char plds[49152];
    const int t = threadIdx.x;
    if (blockIdx.x < 12) {
        float* wl = (float*)plds;                 // [64*192]
        const int h = blockIdx.x;
        const float* Wh = Wqkv + (long)h * (64 * 192);
        for (int i = t; i < 64 * 192; i += 256) wl[i] = Wh[i];
        __syncthreads();
        for (int c = t; c < 1536; c += 256) {
            int row = c >> 3, kc = (c & 7) ^ (row & 7);
            u16x8 v;
            #pragma unroll
            for (int j = 0; j < 8; ++j) v[j] = f2bf1(wl[(kc * 8 + j) * 192 + row]);
            *(u16x8*)&Wt_sw[(long)h * 12288 + c * 8] = v;
        }
    } else {
        float (*tile)[33] = (float(*)[33])plds;   // [32][33]
        const int idx = blockIdx.x - 12;          // 0..575
        const int kb = (idx % 24) * 32, nb = (idx / 24) * 32;
        const int tx = t & 31, ty = t >> 5;
        for (int r = ty; r < 32; r += 8)
            tile[r][tx] = W[(long)(kb + r) * FEATS + nb + tx];
        __syncthreads();
        for (int r = ty; r < 32; r += 8)
            Wt[(long)(nb + r) * FEATS + kb + tx] = f2bf1(tile[tx][r]);
    }
}

// ---------------------------------------------------------------------------
// K1: FUSED qkv + attention — byte-exact revert to the validated 119.9-config
// (one 512-thr block per (b,h), 80.9KB LDS, Pl aliases Ql, runtime tt loop,
// plain attn store). Occupancy is register-bound (~3 waves/SIMD); R12 showed
// unroll/setprio neutral — this architecture is converged.
// ---------------------------------------------------------------------------
__global__ __launch_bounds__(512, 4) void qkv_attn_fused(
    const float* __restrict__ x, const unsigned short* __restrict__ Wt_sw,
    const float* __restrict__ bqkv, unsigned short* __restrict__ attn)
{
    __shared__ __align__(16) char lds[80912];
    unsigned short* As  = (unsigned short*)lds;            // 1664 chunks of 8
    unsigned short* Ws  = (unsigned short*)(lds + 26624);  // 1536 chunks
    unsigned short* Ql  = (unsigned short*)lds;            // [208][8ch][8] (over As)
    unsigned short* Kl  = (unsigned short*)(lds + 26624);  // [208][8ch][8] (over Ws)
    unsigned short* Vtl = (unsigned short*)(lds + 53248);  // [64][216] + pad
    unsigned short* Pl  = (unsigned short*)lds;            // [208][40] swz (over Ql)

    const int t  = threadIdx.x;
    const int w  = t >> 6, l = t & 63;
    const int lr = l & 15, g = l >> 4, g4 = g * 4;
    const int b  = blockIdx.x, h = blockIdx.y;

    // ---- zero Vtl arena
    {
        const uint4 z = {0, 0, 0, 0};
        #pragma unroll
        for (int it = 0; it < 4; ++it) {
            int idx = it * 512 + t;
            if (idx < 1729) *(uint4*)&Vtl[idx * 8] = z;
        }
    }
    // ---- stage As: 208 rows x 64 k bf16, XOR-swizzled chunks (rows>=197 = 0)
    #pragma unroll
    for (int it = 0; it < 4; ++it) {
        int p = it * 512 + t;
        if (p < 1664) {
            int row = p >> 3, kc = (p & 7) ^ (row & 7);
            uint4 pk = {0, 0, 0, 0};
            if (row < NN) {
                const float* src = x + ((long)b * NN + row) * FEATS + h * HD + kc * 8;
                const float4 x0 = *(const float4*)src;
                const float4 x1 = *(const float4*)(src + 4);
                pk.x = f2bf2(x0.x, x0.y); pk.y = f2bf2(x0.z, x0.w);
                pk.z = f2bf2(x1.x, x1.y); pk.w = f2bf2(x1.z, x1.w);
            }
            *(uint4*)&As[p * 8] = pk;
        }
    }
    // ---- stage Ws
    const unsigned short* Wh = Wt_sw + (long)h * 12288;
    #pragma unroll
    for (int it = 0; it < 3; ++it) {
        const int cb = it * 512 + w * 64;
        __builtin_amdgcn_global_load_lds(
            (const __attribute__((address_space(1))) void*)(Wh + (cb + l) * 8),
            (__attribute__((address_space(3))) void*)(Ws + cb * 8),
            16, 0, 0);
    }
    __syncthreads();

    // ---- Phase A compute
    const int wn0 = (w & 3) * 48;
    const int f0  = (w >> 2) * 7;
    const int nf_ = (w >> 2) ? 6 : 7;

    bf16x8 bfr[3][2];
    #pragma unroll
    for (int ni = 0; ni < 3; ++ni) {
        const int rn = wn0 + ni * 16 + lr;
        #pragma unroll
        for (int ks = 0; ks < 2; ++ks)
            bfr[ni][ks] = *(const bf16x8*)&Ws[(rn * 8 + ((ks * 4 + g) ^ (rn & 7))) * 8];
    }

    f32x4 acc[7][3];
    #pragma unroll
    for (int ni = 0; ni < 3; ++ni) {
        const int e0 = wn0 + ni * 16;
        if (e0 < 128) {
            const f32x4 bq = *(const f32x4*)&bqkv[h * 192 + e0 + g4];
            #pragma unroll
            for (int mi = 0; mi < 7; ++mi) acc[mi][ni] = bq;
        } else {
            const float bq = bqkv[h * 192 + e0 + lr];
            #pragma unroll
            for (int mi = 0; mi < 7; ++mi)
                #pragma unroll
                for (int r = 0; r < 4; ++r) acc[mi][ni][r] = bq;
        }
    }

    #pragma unroll
    for (int mi = 0; mi < 7; ++mi) {
        if (mi < nf_) {
            const int rA = (f0 + mi) * 16 + lr;
            bf16x8 a0 = *(const bf16x8*)&As[(rA * 8 + ((0 + g) ^ (rA & 7))) * 8];
            bf16x8 a1 = *(const bf16x8*)&As[(rA * 8 + ((4 + g) ^ (rA & 7))) * 8];
            #pragma unroll
            for (int ni = 0; ni < 3; ++ni) {
                const int e0 = wn0 + ni * 16;
                if (e0 < 128) {
                    acc[mi][ni] = __builtin_amdgcn_mfma_f32_16x16x32_bf16(
                        bfr[ni][0], a0, acc[mi][ni], 0, 0, 0);
                    acc[mi][ni] = __builtin_amdgcn_mfma_f32_16x16x32_bf16(
                        bfr[ni][1], a1, acc[mi][ni], 0, 0, 0);
                } else {
                    acc[mi][ni] = __builtin_amdgcn_mfma_f32_16x16x32_bf16(
                        a0, bfr[ni][0], acc[mi][ni], 0, 0, 0);
                    acc[mi][ni] = __builtin_amdgcn_mfma_f32_16x16x32_bf16(
                        a1, bfr[ni][1], acc[mi][ni], 0, 0, 0);
                }
            }
        }
    }
    __syncthreads();

    // ---- write q/k (XOR-chunk swizzled) and v (Vtl [d][n], stride 216)
    #pragma unroll
    for (int mi = 0; mi < 7; ++mi) {
        if (mi < nf_) {
            const int m = (f0 + mi) * 16 + lr;
            #pragma unroll
            for (int ni = 0; ni < 3; ++ni) {
                const int e0 = wn0 + ni * 16;
                uint2 pv;
                pv.x = f2bf2(acc[mi][ni][0], acc[mi][ni][1]);
                pv.y = f2bf2(acc[mi][ni][2], acc[mi][ni][3]);
                if (e0 < 64) {
                    const int c = ((e0 + g4) >> 3) ^ (m & 7);
                    *(uint2*)&Ql[(m * 8 + c) * 8 + (g4 & 7)] = pv;
                } else if (e0 < 128) {
                    const int e = e0 - 64 + g4;
                    const int c = (e >> 3) ^ (m & 7);
                    *(uint2*)&Kl[(m * 8 + c) * 8 + (g4 & 7)] = pv;
                } else {
                    const int d = e0 - 128 + lr;
                    const int n0 = (f0 + mi) * 16 + g4;
                    *(uint2*)&Vtl[d * VS + n0] = pv;
                }
            }
        }
    }
    __syncthreads();

    // ---- Phase B: load qf from Ql, then Pl may alias Ql
    const int nm = (w < 5) ? 2 : 1;        // frags {w, w+8}, 13 total
    bf16x8 qf[2][2];
    #pragma unroll
    for (int mi = 0; mi < 2; ++mi) {
        if (mi == 0 || mi < nm) {
            const int lm = (w + mi * 8) * 16 + lr;
            #pragma unroll
            for (int ks = 0; ks < 2; ++ks)
                qf[mi][ks] = *(const bf16x8*)&Ql[(lm * 8 + ((ks * 4 + g) ^ (lm & 7))) * 8];
        }
    }
    __syncthreads();

    u16x8 ob;
    #pragma unroll
    for (int j = 0; j < 8; ++j) ob[j] = 0x3F80;   // bf16 1.0
    bf16x8 onesf = *(bf16x8*)&ob;

    f32x4 oacc[2][4] = {};
    f32x4 ssum[2] = {};

    for (int tt = 0; tt < 7; ++tt) {
        const int kv0 = tt * 32;
        const int NF2 = (tt == 6) ? 1 : 2;

        bf16x8 kf[2][2];
        #pragma unroll
        for (int nf2 = 0; nf2 < 2; ++nf2) {
            if (nf2 < NF2) {
                const int row = kv0 + nf2 * 16 + lr;
                #pragma unroll
                for (int ks = 0; ks < 2; ++ks)
                    kf[nf2][ks] = *(const bf16x8*)&Kl[(row * 8 + ((ks * 4 + g) ^ (row & 7))) * 8];
            }
        }

        f32x4 s[2][2] = {};
        #pragma unroll
        for (int mi = 0; mi < 2; ++mi) {
            if (mi < nm) {
                #pragma unroll
                for (int nf2 = 0; nf2 < 2; ++nf2) {
                    if (nf2 < NF2) {
                        s[mi][nf2] = __builtin_amdgcn_mfma_f32_16x16x32_bf16(
                            qf[mi][0], kf[nf2][0], s[mi][nf2], 0, 0, 0);
                        s[mi][nf2] = __builtin_amdgcn_mfma_f32_16x16x32_bf16(
                            qf[mi][1], kf[nf2][1], s[mi][nf2], 0, 0, 0);
                    }
                }
            }
        }

        // exp + mask + swizzled Pl write (s[mi][1]=0 at tt=6 -> masked to 0)
        #pragma unroll
        for (int mi = 0; mi < 2; ++mi) {
            if (mi < nm) {
                #pragma unroll
                for (int nf2 = 0; nf2 < 2; ++nf2) {
                    const bool valid = (kv0 + nf2 * 16 + lr) < NN;
                    const int c = nf2 * 2 + (lr >> 3);
                    #pragma unroll
                    for (int r = 0; r < 4; ++r) {
                        float p = __expf(s[mi][nf2][r] * SCALE_INV);
                        p = valid ? p : 0.f;
                        const int q = (w + mi * 8) * 16 + g4 + r;
                        Pl[q * 40 + (c ^ g) * 8 + (lr & 7)] = f2bf1(p);
                    }
                }
            }
        }

        bf16x8 vf[4];
        #pragma unroll
        for (int df = 0; df < 4; ++df)
            vf[df] = *(const bf16x8*)&Vtl[(df * 16 + lr) * VS + kv0 + g * 8];
        #pragma unroll
        for (int mi = 0; mi < 2; ++mi) {
            if (mi < nm) {
                const int q = (w + mi * 8) * 16 + lr;
                bf16x8 pa = *(const bf16x8*)&Pl[q * 40 + (g ^ ((lr >> 2) & 3)) * 8];
                #pragma unroll
                for (int df = 0; df < 4; ++df)
                    oacc[mi][df] = __builtin_amdgcn_mfma_f32_16x16x32_bf16(
                        pa, vf[df], oacc[mi][df], 0, 0, 0);
                ssum[mi] = __builtin_amdgcn_mfma_f32_16x16x32_bf16(
                    pa, onesf, ssum[mi], 0, 0, 0);
            }
        }
    }

    #pragma unroll
    for (int mi = 0; mi < 2; ++mi) {
        if (mi < nm) {
            f32x4 inv;
            #pragma unroll
            for (int r = 0; r < 4; ++r) inv[r] = 1.0f / ssum[mi][r];
            #pragma unroll
            for (int df = 0; df < 4; ++df) {
                #pragma unroll
                for (int r = 0; r < 4; ++r) {
                    const int grow = (w + mi * 8) * 16 + g4 + r;
                    if (grow < NN)
                        attn[((long)b * NN + grow) * FEATS + h * HD + df * 16 + lr]
                            = f2bf1(oacc[mi][df][r] * inv[r]);
                }
            }
        }
    }
}

// ---------------------------------------------------------------------------
// K3: out-projection via MFMA. BM=64 this round: grid 2364 (= 394 x 6),
// 12 KB LDS + acc[2][4] (~70 VGPR) -> 32 waves/CU (2x R11's latency cover),
// finer straggler quantum. m97 2-barrier structure, linear LDS.
// XCD-bijective swizzle (m204 form): 2364 = 4*296 + 4*295; consecutive wk
// share an A-panel (6 per panel) and land on one XCD's L2.
// ---------------------------------------------------------------------------
__global__ __launch_bounds__(256) void outproj_mfma(
    const unsigned short* __restrict__ A,
    const unsigned short* __restrict__ Bt,
    const float* __restrict__ bout, float* __restrict__ out)
{
    __shared__ unsigned short As2[64 * 32];    // 4 KB
    __shared__ unsigned short Bs2[128 * 32];   // 8 KB

    const int t  = threadIdx.x;
    const int w  = t >> 6;
    const int l  = t & 63;
    const int idx = blockIdx.x;                // 0..2363
    const int xcd = idx & 7, j = idx >> 3;
    const int start = (xcd < 4) ? xcd * 296 : 1184 + (xcd - 4) * 295;
    const int wk = start + j;
    const int m0 = (wk / 6) * 64;
    const int n0 = (wk % 6) * 128;
    const int wm = (w >> 1) * 32;
    const int wn = (w & 1) * 64;
    const int lr = l & 15;
    const int lk = l >> 4;

    f32x4 acc[2][4] = {};

    for (int k0 = 0; k0 < FEATS; k0 += 32) {
        {   // A: 64x32 = 4KB, one 16B chunk per thread
            const int row = t >> 2;
            const int col = (t & 3) * 8;
            __builtin_amdgcn_global_load_lds(
                (const __attribute__((address_space(1))) void*)
                    (A + (long)(m0 + row) * FEATS + k0 + col),
                (__attribute__((address_space(3))) void*)(As2 + w * 512),
                16, 0, 0);
        }
        #pragma unroll
        for (int c = 0; c < 2; ++c) {   // B: 128x32 = 8KB
            const int p   = c * 256 + t;
            const int row = p >> 2;
            const int col = (p & 3) * 8;
            __builtin_amdgcn_global_load_lds(
                (const __attribute__((address_space(1))) void*)
                    (Bt + (long)(n0 + row) * FEATS + k0 + col),
                (__attribute__((address_space(3))) void*)(Bs2 + (c * 256 + w * 64) * 8),
                16, 0, 0);
        }
        __syncthreads();

        bf16x8 af[2], bfr[4];
        #pragma unroll
        for (int mi = 0; mi < 2; ++mi)
            af[mi] = *(const bf16x8*)(As2 + (wm + mi * 16 + lr) * 32 + lk * 8);
        #pragma unroll
        for (int ni = 0; ni < 4; ++ni)
            bfr[ni] = *(const bf16x8*)(Bs2 + (wn + ni * 16 + lr) * 32 + lk * 8);
        #pragma unroll
        for (int mi = 0; mi < 2; ++mi)
            #pragma unroll
            for (int ni = 0; ni < 4; ++ni)
                acc[mi][ni] = __builtin_amdgcn_mfma_f32_16x16x32_bf16(
                    af[mi], bfr[ni], acc[mi][ni], 0, 0, 0);
        __syncthreads();
    }

    float bv[4];
    #pragma unroll
    for (int ni = 0; ni < 4; ++ni) bv[ni] = bout[n0 + wn + ni * 16 + lr];
    #pragma unroll
    for (int mi = 0; mi < 2; ++mi) {
        #pragma unroll
        for (int ni = 0; ni < 4; ++ni) {
            const int gcol = n0 + wn + ni * 16 + lr;
            #pragma unroll
            for (int r = 0; r < 4; ++r) {
                const int grow = m0 + wm + mi * 16 + lk * 4 + r;
                out[(long)grow * FEATS + gcol] = acc[mi][ni][r] + bv[ni];
            }
        }
    }
}

// ---------------------------------------------------------------------------
extern "C" void kernel_launch(void* const* d_in, const int* in_sizes, int n_in,
                              void* d_out, int out_size, void* d_ws, size_t ws_size,
                              hipStream_t stream)
{
    const float* x    = (const float*)d_in[0];
    const float* Wqkv = (const float*)d_in[1];
    const float* bqkv = (const float*)d_in[2];
    const float* Wout = (const float*)d_in[3];
    const float* bout = (const float*)d_in[4];
    float* out = (float*)d_out;

    unsigned short* wsp = (unsigned short*)d_ws;
    const long S = (long)M_TOT * FEATS;               // 19,365,888
    unsigned short* attn  = wsp;
    unsigned short* Wt_sw = wsp + S;                  // 147,456 shorts
    unsigned short* Wt    = wsp + S + 150000;         // 589,824 shorts

    prep_kernel<<<dim3(588), 256, 0, stream>>>(Wqkv, Wt_sw, Wout, Wt);

    qkv_attn_fused<<<dim3(BB, HEADS), 512, 0, stream>>>(x, Wt_sw, bqkv, attn);

    outproj_mfma<<<dim3(2364), 256, 0, stream>>>(attn, Wt, bout, out);
}

// Round 15
// 116.362 us; speedup vs baseline: 1.1403x; 1.1403x over previous
//
#include <hip/hip_runtime.h>
#include <hip/hip_bf16.h>

#define FEATS 768
#define HEADS 12
#define HD    64
#define BB    128
#define NN    197
#define M_TOT (BB * NN)   // 25216
#define SCALE_INV (3.6084391824351615e-02f)  // 1/sqrt(768)
#define VS    216          // Vtl row stride in shorts

typedef __bf16 bf16x8 __attribute__((ext_vector_type(8)));
typedef float  f32x4  __attribute__((ext_vector_type(4)));
typedef unsigned short u16x8 __attribute__((ext_vector_type(8)));

__device__ __forceinline__ unsigned short f2bf1(float f) {
    __bf16 h = (__bf16)f;
    return *(unsigned short*)&h;
}
__device__ __forceinline__ unsigned int f2bf2(float lo, float hi) {
    return (unsigned int)f2bf1(lo) | ((unsigned int)f2bf1(hi) << 16);
}

// ---------------------------------------------------------------------------
// K0: merged prep (validated R13). Blocks 0..11: W_qkv -> Wt_sw.
// Blocks 12..587: W_out f32 [k][n] -> bf16 Wt [n][k] (plain).
// ---------------------------------------------------------------------------
__global__ __launch_bounds__(256) void prep_kernel(
    const float* __restrict__ Wqkv, unsigned short* __restrict__ Wt_sw,
    const float* __restrict__ W,    unsigned short* __restrict__ Wt)
{
    __shared__ __align__(16) char plds[49152];
    const int t = threadIdx.x;
    if (blockIdx.x < 12) {
        float* wl = (float*)plds;                 // [64*192]
        const int h = blockIdx.x;
        const float* Wh = Wqkv + (long)h * (64 * 192);
        for (int i = t; i < 64 * 192; i += 256) wl[i] = Wh[i];
        __syncthreads();
        for (int c = t; c < 1536; c += 256) {
            int row = c >> 3, kc = (c & 7) ^ (row & 7);
            u16x8 v;
            #pragma unroll
            for (int j = 0; j < 8; ++j) v[j] = f2bf1(wl[(kc * 8 + j) * 192 + row]);
            *(u16x8*)&Wt_sw[(long)h * 12288 + c * 8] = v;
        }
    } else {
        float (*tile)[33] = (float(*)[33])plds;   // [32][33]
        const int idx = blockIdx.x - 12;          // 0..575
        const int kb = (idx % 24) * 32, nb = (idx / 24) * 32;
        const int tx = t & 31, ty = t >> 5;
        for (int r = ty; r < 32; r += 8)
            tile[r][tx] = W[(long)(kb + r) * FEATS + nb + tx];
        __syncthreads();
        for (int r = ty; r < 32; r += 8)
            Wt[(long)(nb + r) * FEATS + kb + tx] = f2bf1(tile[tx][r]);
    }
}

// ---------------------------------------------------------------------------
// K1: FUSED qkv + attention — validated R11 config (119.9-era), unchanged.
// One 512-thr block per (b,h); 80.9KB LDS; Pl aliases Ql; runtime tt loop.
// Register-floor-bound at ~3 waves/SIMD (phase-A acc = 78+ regs/lane min).
// ---------------------------------------------------------------------------
__global__ __launch_bounds__(512, 4) void qkv_attn_fused(
    const float* __restrict__ x, const unsigned short* __restrict__ Wt_sw,
    const float* __restrict__ bqkv, unsigned short* __restrict__ attn)
{
    __shared__ __align__(16) char lds[80912];
    unsigned short* As  = (unsigned short*)lds;            // 1664 chunks of 8
    unsigned short* Ws  = (unsigned short*)(lds + 26624);  // 1536 chunks
    unsigned short* Ql  = (unsigned short*)lds;            // [208][8ch][8] (over As)
    unsigned short* Kl  = (unsigned short*)(lds + 26624);  // [208][8ch][8] (over Ws)
    unsigned short* Vtl = (unsigned short*)(lds + 53248);  // [64][216] + pad
    unsigned short* Pl  = (unsigned short*)lds;            // [208][40] swz (over Ql)

    const int t  = threadIdx.x;
    const int w  = t >> 6, l = t & 63;
    const int lr = l & 15, g = l >> 4, g4 = g * 4;
    const int b  = blockIdx.x, h = blockIdx.y;

    // ---- zero Vtl arena
    {
        const uint4 z = {0, 0, 0, 0};
        #pragma unroll
        for (int it = 0; it < 4; ++it) {
            int idx = it * 512 + t;
            if (idx < 1729) *(uint4*)&Vtl[idx * 8] = z;
        }
    }
    // ---- stage As: 208 rows x 64 k bf16, XOR-swizzled chunks (rows>=197 = 0)
    #pragma unroll
    for (int it = 0; it < 4; ++it) {
        int p = it * 512 + t;
        if (p < 1664) {
            int row = p >> 3, kc = (p & 7) ^ (row & 7);
            uint4 pk = {0, 0, 0, 0};
            if (row < NN) {
                const float* src = x + ((long)b * NN + row) * FEATS + h * HD + kc * 8;
                const float4 x0 = *(const float4*)src;
                const float4 x1 = *(const float4*)(src + 4);
                pk.x = f2bf2(x0.x, x0.y); pk.y = f2bf2(x0.z, x0.w);
                pk.z = f2bf2(x1.x, x1.y); pk.w = f2bf2(x1.z, x1.w);
            }
            *(uint4*)&As[p * 8] = pk;
        }
    }
    // ---- stage Ws
    const unsigned short* Wh = Wt_sw + (long)h * 12288;
    #pragma unroll
    for (int it = 0; it < 3; ++it) {
        const int cb = it * 512 + w * 64;
        __builtin_amdgcn_global_load_lds(
            (const __attribute__((address_space(1))) void*)(Wh + (cb + l) * 8),
            (__attribute__((address_space(3))) void*)(Ws + cb * 8),
            16, 0, 0);
    }
    __syncthreads();

    // ---- Phase A compute
    const int wn0 = (w & 3) * 48;
    const int f0  = (w >> 2) * 7;
    const int nf_ = (w >> 2) ? 6 : 7;

    bf16x8 bfr[3][2];
    #pragma unroll
    for (int ni = 0; ni < 3; ++ni) {
        const int rn = wn0 + ni * 16 + lr;
        #pragma unroll
        for (int ks = 0; ks < 2; ++ks)
            bfr[ni][ks] = *(const bf16x8*)&Ws[(rn * 8 + ((ks * 4 + g) ^ (rn & 7))) * 8];
    }

    f32x4 acc[7][3];
    #pragma unroll
    for (int ni = 0; ni < 3; ++ni) {
        const int e0 = wn0 + ni * 16;
        if (e0 < 128) {
            const f32x4 bq = *(const f32x4*)&bqkv[h * 192 + e0 + g4];
            #pragma unroll
            for (int mi = 0; mi < 7; ++mi) acc[mi][ni] = bq;
        } else {
            const float bq = bqkv[h * 192 + e0 + lr];
            #pragma unroll
            for (int mi = 0; mi < 7; ++mi)
                #pragma unroll
                for (int r = 0; r < 4; ++r) acc[mi][ni][r] = bq;
        }
    }

    #pragma unroll
    for (int mi = 0; mi < 7; ++mi) {
        if (mi < nf_) {
            const int rA = (f0 + mi) * 16 + lr;
            bf16x8 a0 = *(const bf16x8*)&As[(rA * 8 + ((0 + g) ^ (rA & 7))) * 8];
            bf16x8 a1 = *(const bf16x8*)&As[(rA * 8 + ((4 + g) ^ (rA & 7))) * 8];
            #pragma unroll
            for (int ni = 0; ni < 3; ++ni) {
                const int e0 = wn0 + ni * 16;
                if (e0 < 128) {
                    acc[mi][ni] = __builtin_amdgcn_mfma_f32_16x16x32_bf16(
                        bfr[ni][0], a0, acc[mi][ni], 0, 0, 0);
                    acc[mi][ni] = __builtin_amdgcn_mfma_f32_16x16x32_bf16(
                        bfr[ni][1], a1, acc[mi][ni], 0, 0, 0);
                } else {
                    acc[mi][ni] = __builtin_amdgcn_mfma_f32_16x16x32_bf16(
                        a0, bfr[ni][0], acc[mi][ni], 0, 0, 0);
                    acc[mi][ni] = __builtin_amdgcn_mfma_f32_16x16x32_bf16(
                        a1, bfr[ni][1], acc[mi][ni], 0, 0, 0);
                }
            }
        }
    }
    __syncthreads();

    // ---- write q/k (XOR-chunk swizzled) and v (Vtl [d][n], stride 216)
    #pragma unroll
    for (int mi = 0; mi < 7; ++mi) {
        if (mi < nf_) {
            const int m = (f0 + mi) * 16 + lr;
            #pragma unroll
            for (int ni = 0; ni < 3; ++ni) {
                const int e0 = wn0 + ni * 16;
                uint2 pv;
                pv.x = f2bf2(acc[mi][ni][0], acc[mi][ni][1]);
                pv.y = f2bf2(acc[mi][ni][2], acc[mi][ni][3]);
                if (e0 < 64) {
                    const int c = ((e0 + g4) >> 3) ^ (m & 7);
                    *(uint2*)&Ql[(m * 8 + c) * 8 + (g4 & 7)] = pv;
                } else if (e0 < 128) {
                    const int e = e0 - 64 + g4;
                    const int c = (e >> 3) ^ (m & 7);
                    *(uint2*)&Kl[(m * 8 + c) * 8 + (g4 & 7)] = pv;
                } else {
                    const int d = e0 - 128 + lr;
                    const int n0 = (f0 + mi) * 16 + g4;
                    *(uint2*)&Vtl[d * VS + n0] = pv;
                }
            }
        }
    }
    __syncthreads();

    // ---- Phase B: load qf from Ql, then Pl may alias Ql
    const int nm = (w < 5) ? 2 : 1;        // frags {w, w+8}, 13 total
    bf16x8 qf[2][2];
    #pragma unroll
    for (int mi = 0; mi < 2; ++mi) {
        if (mi == 0 || mi < nm) {
            const int lm = (w + mi * 8) * 16 + lr;
            #pragma unroll
            for (int ks = 0; ks < 2; ++ks)
                qf[mi][ks] = *(const bf16x8*)&Ql[(lm * 8 + ((ks * 4 + g) ^ (lm & 7))) * 8];
        }
    }
    __syncthreads();

    u16x8 ob;
    #pragma unroll
    for (int j = 0; j < 8; ++j) ob[j] = 0x3F80;   // bf16 1.0
    bf16x8 onesf = *(bf16x8*)&ob;

    f32x4 oacc[2][4] = {};
    f32x4 ssum[2] = {};

    for (int tt = 0; tt < 7; ++tt) {
        const int kv0 = tt * 32;
        const int NF2 = (tt == 6) ? 1 : 2;

        bf16x8 kf[2][2];
        #pragma unroll
        for (int nf2 = 0; nf2 < 2; ++nf2) {
            if (nf2 < NF2) {
                const int row = kv0 + nf2 * 16 + lr;
                #pragma unroll
                for (int ks = 0; ks < 2; ++ks)
                    kf[nf2][ks] = *(const bf16x8*)&Kl[(row * 8 + ((ks * 4 + g) ^ (row & 7))) * 8];
            }
        }

        f32x4 s[2][2] = {};
        #pragma unroll
        for (int mi = 0; mi < 2; ++mi) {
            if (mi < nm) {
                #pragma unroll
                for (int nf2 = 0; nf2 < 2; ++nf2) {
                    if (nf2 < NF2) {
                        s[mi][nf2] = __builtin_amdgcn_mfma_f32_16x16x32_bf16(
                            qf[mi][0], kf[nf2][0], s[mi][nf2], 0, 0, 0);
                        s[mi][nf2] = __builtin_amdgcn_mfma_f32_16x16x32_bf16(
                            qf[mi][1], kf[nf2][1], s[mi][nf2], 0, 0, 0);
                    }
                }
            }
        }

        // exp + mask + swizzled Pl write (s[mi][1]=0 at tt=6 -> masked to 0)
        #pragma unroll
        for (int mi = 0; mi < 2; ++mi) {
            if (mi < nm) {
                #pragma unroll
                for (int nf2 = 0; nf2 < 2; ++nf2) {
                    const bool valid = (kv0 + nf2 * 16 + lr) < NN;
                    const int c = nf2 * 2 + (lr >> 3);
                    #pragma unroll
                    for (int r = 0; r < 4; ++r) {
                        float p = __expf(s[mi][nf2][r] * SCALE_INV);
                        p = valid ? p : 0.f;
                        const int q = (w + mi * 8) * 16 + g4 + r;
                        Pl[q * 40 + (c ^ g) * 8 + (lr & 7)] = f2bf1(p);
                    }
                }
            }
        }

        bf16x8 vf[4];
        #pragma unroll
        for (int df = 0; df < 4; ++df)
            vf[df] = *(const bf16x8*)&Vtl[(df * 16 + lr) * VS + kv0 + g * 8];
        #pragma unroll
        for (int mi = 0; mi < 2; ++mi) {
            if (mi < nm) {
                const int q = (w + mi * 8) * 16 + lr;
                bf16x8 pa = *(const bf16x8*)&Pl[q * 40 + (g ^ ((lr >> 2) & 3)) * 8];
                #pragma unroll
                for (int df = 0; df < 4; ++df)
                    oacc[mi][df] = __builtin_amdgcn_mfma_f32_16x16x32_bf16(
                        pa, vf[df], oacc[mi][df], 0, 0, 0);
                ssum[mi] = __builtin_amdgcn_mfma_f32_16x16x32_bf16(
                    pa, onesf, ssum[mi], 0, 0, 0);
            }
        }
    }

    #pragma unroll
    for (int mi = 0; mi < 2; ++mi) {
        if (mi < nm) {
            f32x4 inv;
            #pragma unroll
            for (int r = 0; r < 4; ++r) inv[r] = 1.0f / ssum[mi][r];
            #pragma unroll
            for (int df = 0; df < 4; ++df) {
                #pragma unroll
                for (int r = 0; r < 4; ++r) {
                    const int grow = (w + mi * 8) * 16 + g4 + r;
                    if (grow < NN)
                        attn[((long)b * NN + grow) * FEATS + h * HD + df * 16 + lr]
                            = f2bf1(oacc[mi][df][r] * inv[r]);
                }
            }
        }
    }
}

// ---------------------------------------------------------------------------
// K3: out-projection — validated R11-exact (BM=BN=128, BK=32, m97 structure,
// XCD-bijective-1182). Runs at the m97-structure ceiling (~825 TF here);
// R14 proved smaller tiles regress (barrier/conflict exposure).
// ---------------------------------------------------------------------------
__global__ __launch_bounds__(256) void outproj_mfma(
    const unsigned short* __restrict__ A,
    const unsigned short* __restrict__ Bt,
    const float* __restrict__ bout, float* __restrict__ out)
{
    __shared__ unsigned short As[128 * 32];
    __shared__ unsigned short Bs[128 * 32];

    const int t  = threadIdx.x;
    const int w  = t >> 6;
    const int l  = t & 63;
    const int idx  = blockIdx.x;             // 0..1181
    const int xcd  = idx & 7, qq = idx >> 3;
    const int start = (xcd < 6) ? xcd * 148 : 888 + (xcd - 6) * 147;
    const int wk = start + qq;
    const int m0 = (wk / 6) * 128;
    const int n0 = (wk % 6) * 128;
    const int wm = (w >> 1) * 64;
    const int wn = (w & 1) * 64;
    const int lr = l & 15;
    const int lk = l >> 4;

    f32x4 acc[4][4] = {};

    for (int k0 = 0; k0 < FEATS; k0 += 32) {
        #pragma unroll
        for (int c = 0; c < 2; ++c) {
            const int off = c * 4096 + t * 16;
            const int row = off >> 6;
            const int col = (off & 63) >> 1;
            const unsigned short* gA = A  + (long)(m0 + row) * FEATS + k0 + col;
            const unsigned short* gB = Bt + (long)(n0 + row) * FEATS + k0 + col;
            __builtin_amdgcn_global_load_lds(
                (const __attribute__((address_space(1))) void*)gA,
                (__attribute__((address_space(3))) void*)(As + c * 2048 + w * 512),
                16, 0, 0);
            __builtin_amdgcn_global_load_lds(
                (const __attribute__((address_space(1))) void*)gB,
                (__attribute__((address_space(3))) void*)(Bs + c * 2048 + w * 512),
                16, 0, 0);
        }
        __syncthreads();

        bf16x8 af[4], bfr[4];
        #pragma unroll
        for (int mi = 0; mi < 4; ++mi)
            af[mi] = *(const bf16x8*)(As + (wm + mi * 16 + lr) * 32 + lk * 8);
        #pragma unroll
        for (int ni = 0; ni < 4; ++ni)
            bfr[ni] = *(const bf16x8*)(Bs + (wn + ni * 16 + lr) * 32 + lk * 8);
        #pragma unroll
        for (int mi = 0; mi < 4; ++mi)
            #pragma unroll
            for (int ni = 0; ni < 4; ++ni)
                acc[mi][ni] = __builtin_amdgcn_mfma_f32_16x16x32_bf16(
                    af[mi], bfr[ni], acc[mi][ni], 0, 0, 0);
        __syncthreads();
    }

    float bv[4];
    #pragma unroll
    for (int ni = 0; ni < 4; ++ni) bv[ni] = bout[n0 + wn + ni * 16 + lr];
    #pragma unroll
    for (int mi = 0; mi < 4; ++mi) {
        #pragma unroll
        for (int ni = 0; ni < 4; ++ni) {
            const int gcol = n0 + wn + ni * 16 + lr;
            #pragma unroll
            for (int r = 0; r < 4; ++r) {
                const int grow = m0 + wm + mi * 16 + lk * 4 + r;
                out[(long)grow * FEATS + gcol] = acc[mi][ni][r] + bv[ni];
            }
        }
    }
}

// ---------------------------------------------------------------------------
extern "C" void kernel_launch(void* const* d_in, const int* in_sizes, int n_in,
                              void* d_out, int out_size, void* d_ws, size_t ws_size,
                              hipStream_t stream)
{
    const float* x    = (const float*)d_in[0];
    const float* Wqkv = (const float*)d_in[1];
    const float* bqkv = (const float*)d_in[2];
    const float* Wout = (const float*)d_in[3];
    const float* bout = (const float*)d_in[4];
    float* out = (float*)d_out;

    unsigned short* wsp = (unsigned short*)d_ws;
    const long S = (long)M_TOT * FEATS;               // 19,365,888
    unsigned short* attn  = wsp;
    unsigned short* Wt_sw = wsp + S;                  // 147,456 shorts
    unsigned short* Wt    = wsp + S + 150000;         // 589,824 shorts

    prep_kernel<<<dim3(588), 256, 0, stream>>>(Wqkv, Wt_sw, Wout, Wt);

    qkv_attn_fused<<<dim3(BB, HEADS), 512, 0, stream>>>(x, Wt_sw, bqkv, attn);

    outproj_mfma<<<dim3(1182), 256, 0, stream>>>(attn, Wt, bout, out);
}